// Round 1
// baseline (852.698 us; speedup 1.0000x reference)
//
#include <hip/hip_runtime.h>
#include <math.h>

typedef __attribute__((ext_vector_type(8))) short bf16x8;
typedef __attribute__((ext_vector_type(4))) float f32x4;

#define NB 4
#define NL 2048
#define ND 2048
#define NH 16
#define NDH 128
#define NDC 512
#define NROWS (NB*NL)

__device__ __forceinline__ unsigned short f2bf(float f) {
  unsigned int u = __float_as_uint(f);
  u += 0x7fffu + ((u >> 16) & 1u);
  return (unsigned short)(u >> 16);
}
__device__ __forceinline__ float bf2f(unsigned short h) {
  return __uint_as_float(((unsigned int)h) << 16);
}

__device__ __forceinline__ void gld16(const void* g, void* l) {
  __builtin_amdgcn_global_load_lds((const __attribute__((address_space(1))) void*)g,
                                   (__attribute__((address_space(3))) void*)l, 16, 0, 0);
}

// ---------------- fp32 -> bf16 convert ----------------
__global__ void cvt_kernel(const float4* __restrict__ in, ushort4* __restrict__ out, int n4) {
  int stride = gridDim.x * blockDim.x;
  for (int i = blockIdx.x * blockDim.x + threadIdx.x; i < n4; i += stride) {
    float4 v = in[i];
    ushort4 o;
    o.x = f2bf(v.x); o.y = f2bf(v.y); o.z = f2bf(v.z); o.w = f2bf(v.w);
    out[i] = o;
  }
}

// ---------------- NT GEMM: C[M,N] = A[M,K] * B[N,K]^T (bf16 in, fp32 acc) ----------------
// 128x128 tile, BK=32, 256 threads = 4 waves in 2x2, each wave 64x64 (4x4 frags of 16x16x32)
template<int OUT_F32>
__global__ __launch_bounds__(256) void gemm_nt(const unsigned short* __restrict__ A,
                                               const unsigned short* __restrict__ Bm,
                                               void* __restrict__ Cv,
                                               int M, int N, int K) {
  __shared__ unsigned short As[128 * 32];
  __shared__ unsigned short Bs[128 * 32];
  const int tid = threadIdx.x;
  const int wid = tid >> 6;
  const int lane = tid & 63;
  const int wr = wid >> 1, wc = wid & 1;
  const long bm = blockIdx.y, bn = blockIdx.x;
  const int r15 = lane & 15;
  const int koff = (lane >> 4) * 8;
  const int srow = lane >> 2;          // 0..15 within wave's 16-row slab
  const int scol = (lane & 3) * 8;

  f32x4 acc[4][4];
#pragma unroll
  for (int m = 0; m < 4; ++m)
#pragma unroll
    for (int n = 0; n < 4; ++n) acc[m][n] = (f32x4){0.f, 0.f, 0.f, 0.f};

  const unsigned short* Ablk = A + (bm * 128 + wid * 16 + srow) * (long)K + scol;
  const unsigned short* Bblk = Bm + (bn * 128 + wid * 16 + srow) * (long)K + scol;
  unsigned short* AsW = As + wid * 16 * 32;   // wave-uniform LDS dest base
  unsigned short* BsW = Bs + wid * 16 * 32;

  for (int kk = 0; kk < K; kk += 32) {
    __syncthreads();
#pragma unroll
    for (int j = 0; j < 2; ++j) {
      gld16(Ablk + (long)j * 64 * K + kk, AsW + j * 64 * 32);
      gld16(Bblk + (long)j * 64 * K + kk, BsW + j * 64 * 32);
    }
    __syncthreads();
    bf16x8 af[4], bfr[4];
#pragma unroll
    for (int m = 0; m < 4; ++m)
      af[m] = *(const bf16x8*)(As + (wr * 64 + m * 16 + r15) * 32 + koff);
#pragma unroll
    for (int n = 0; n < 4; ++n)
      bfr[n] = *(const bf16x8*)(Bs + (wc * 64 + n * 16 + r15) * 32 + koff);
#pragma unroll
    for (int m = 0; m < 4; ++m)
#pragma unroll
      for (int n = 0; n < 4; ++n)
        acc[m][n] = __builtin_amdgcn_mfma_f32_16x16x32_bf16(af[m], bfr[n], acc[m][n], 0, 0, 0);
  }

  const int rr = (lane >> 4) * 4;
#pragma unroll
  for (int m = 0; m < 4; ++m) {
#pragma unroll
    for (int n = 0; n < 4; ++n) {
      long row0 = bm * 128 + wr * 64 + m * 16 + rr;
      long col = bn * 128 + wc * 64 + n * 16 + r15;
#pragma unroll
      for (int r = 0; r < 4; ++r) {
        float v = acc[m][n][r];
        if (OUT_F32) ((float*)Cv)[(row0 + r) * (long)N + col] = v;
        else ((unsigned short*)Cv)[(row0 + r) * (long)N + col] = f2bf(v);
      }
    }
  }
}

// ---------------- RoPE in-place on (NROWS, ND) bf16, per-head pairs (d, d+64) ----------------
__global__ void rope_kernel(unsigned short* __restrict__ Qb, const float* __restrict__ cosb,
                            const float* __restrict__ sinb, float scale) {
  const long row = blockIdx.x;
  const float* cr = cosb + row * NDH;
  const float* sr = sinb + row * NDH;
  unsigned short* q = Qb + row * (long)ND;
  for (int p = threadIdx.x; p < NH * 64; p += blockDim.x) {
    int h = p >> 6, d = p & 63;
    int i1 = h * 128 + d, i2 = i1 + 64;
    float q1 = bf2f(q[i1]), q2 = bf2f(q[i2]);
    float c1 = cr[d], c2 = cr[d + 64], s1 = sr[d], s2 = sr[d + 64];
    float o1 = (q1 * c1 - q2 * s1) * scale;
    float o2 = (q2 * c2 + q1 * s2) * scale;
    q[i1] = f2bf(o1);
    q[i2] = f2bf(o2);
  }
}

// ---------------- Flash attention ----------------
// grid (NL/64, NB*NH); 256 thr = 4 waves; wave owns 16 Q rows; KV tile = 64 keys
__global__ __launch_bounds__(256) void flash_attn(const unsigned short* __restrict__ Qb,
                                                  const unsigned short* __restrict__ Kb,
                                                  const unsigned short* __restrict__ Vb,
                                                  unsigned short* __restrict__ Ob) {
  __shared__ unsigned short Ks[64 * 136];      // 64 keys x 128 d, pad +8
  __shared__ unsigned short Vt[128 * 72];      // transposed: d x keys, pad +8, key XOR-swizzled
  __shared__ unsigned short Ps[4][16 * 72];    // per-wave P tile, pad +8

  const int tid = threadIdx.x, wid = tid >> 6, lane = tid & 63;
  const int r15 = lane & 15, khi = lane >> 4;
  const int bh = blockIdx.y, qt = blockIdx.x;
  const int b = bh >> 4, h = bh & 15;
  const long rowbase = (long)b * NL;
  const int colbase = h * NDH;

  // Q fragments (rows qt*64 + wid*16 + r15, k chunks of 32)
  bf16x8 qf[4];
  {
    const unsigned short* qp =
        Qb + (rowbase + qt * 64 + wid * 16 + r15) * (long)ND + colbase + khi * 8;
#pragma unroll
    for (int kc = 0; kc < 4; ++kc) qf[kc] = *(const bf16x8*)(qp + kc * 32);
  }

  f32x4 oacc[8];
#pragma unroll
  for (int dt = 0; dt < 8; ++dt) oacc[dt] = (f32x4){0.f, 0.f, 0.f, 0.f};
  float mrow[4] = {-1e30f, -1e30f, -1e30f, -1e30f};
  float lrow[4] = {0.f, 0.f, 0.f, 0.f};

  for (int kt = 0; kt < NL / 64; ++kt) {
    __syncthreads();
    // stage K row-major + V transposed (key-swizzled)
#pragma unroll
    for (int j = 0; j < 4; ++j) {
      int c = tid + 256 * j;           // 0..1023
      int key = c >> 4;
      int c8 = (c & 15) * 8;
      const long grow = (rowbase + kt * 64 + key) * (long)ND + colbase + c8;
      bf16x8 kv = *(const bf16x8*)(Kb + grow);
      *(bf16x8*)(Ks + key * 136 + c8) = kv;
      bf16x8 vv = *(const bf16x8*)(Vb + grow);
#pragma unroll
      for (int i = 0; i < 8; ++i) {
        int d = c8 + i;
        int kcol = key ^ (((d >> 3) & 7) << 3);
        Vt[d * 72 + kcol] = (unsigned short)vv[i];
      }
    }
    __syncthreads();

    // S = Q K^T  (wave's 16 rows x 64 keys)
    f32x4 sacc[4];
#pragma unroll
    for (int n = 0; n < 4; ++n) {
      sacc[n] = (f32x4){0.f, 0.f, 0.f, 0.f};
#pragma unroll
      for (int kc = 0; kc < 4; ++kc) {
        bf16x8 kf = *(const bf16x8*)(Ks + (n * 16 + r15) * 136 + kc * 32 + khi * 8);
        sacc[n] = __builtin_amdgcn_mfma_f32_16x16x32_bf16(qf[kc], kf, sacc[n], 0, 0, 0);
      }
    }

    // online softmax per owned row slot r (row = khi*4 + r)
#pragma unroll
    for (int r = 0; r < 4; ++r) {
      float v = fmaxf(fmaxf(sacc[0][r], sacc[1][r]), fmaxf(sacc[2][r], sacc[3][r]));
      v = fmaxf(v, __shfl_xor(v, 1));
      v = fmaxf(v, __shfl_xor(v, 2));
      v = fmaxf(v, __shfl_xor(v, 4));
      v = fmaxf(v, __shfl_xor(v, 8));
      float mnew = fmaxf(mrow[r], v);
      float corr = __expf(mrow[r] - mnew);
      mrow[r] = mnew;
      float ps = 0.f;
#pragma unroll
      for (int n = 0; n < 4; ++n) {
        float pv = __expf(sacc[n][r] - mnew);
        sacc[n][r] = pv;
        ps += pv;
      }
      ps += __shfl_xor(ps, 1);
      ps += __shfl_xor(ps, 2);
      ps += __shfl_xor(ps, 4);
      ps += __shfl_xor(ps, 8);
      lrow[r] = lrow[r] * corr + ps;
#pragma unroll
      for (int dt = 0; dt < 8; ++dt) oacc[dt][r] *= corr;
      int prow = khi * 4 + r;
#pragma unroll
      for (int n = 0; n < 4; ++n)
        Ps[wid][prow * 72 + n * 16 + r15] = f2bf(sacc[n][r]);
    }
    asm volatile("s_waitcnt lgkmcnt(0)" ::: "memory");
    __builtin_amdgcn_sched_barrier(0);

    // PV: oacc += P(16x64) * V(64x128)
#pragma unroll
    for (int kc2 = 0; kc2 < 2; ++kc2) {
      bf16x8 pa = *(const bf16x8*)(Ps[wid] + r15 * 72 + kc2 * 32 + khi * 8);
#pragma unroll
      for (int dt = 0; dt < 8; ++dt) {
        int d = dt * 16 + r15;
        int kb = (kc2 * 32 + khi * 8) ^ (((d >> 3) & 7) << 3);
        bf16x8 vf = *(const bf16x8*)(Vt + d * 72 + kb);
        oacc[dt] = __builtin_amdgcn_mfma_f32_16x16x32_bf16(pa, vf, oacc[dt], 0, 0, 0);
      }
    }
  }

  // epilogue: O / l -> bf16
#pragma unroll
  for (int dt = 0; dt < 8; ++dt) {
#pragma unroll
    for (int r = 0; r < 4; ++r) {
      long row = rowbase + qt * 64 + wid * 16 + khi * 4 + r;
      float v = oacc[dt][r] / lrow[r];
      Ob[row * (long)ND + colbase + dt * 16 + r15] = f2bf(v);
    }
  }
}

// ---------------- launch ----------------
extern "C" void kernel_launch(void* const* d_in, const int* in_sizes, int n_in,
                              void* d_out, int out_size, void* d_ws, size_t ws_size,
                              hipStream_t stream) {
  const float* x = (const float*)d_in[0];
  const float* rope_cos = (const float*)d_in[1];
  const float* rope_sin = (const float*)d_in[2];
  const float* W_q = (const float*)d_in[3];
  const float* W_dkv = (const float*)d_in[4];
  const float* W_uk = (const float*)d_in[5];
  const float* W_uv = (const float*)d_in[6];
  const float* W_o = (const float*)d_in[7];
  float* out = (float*)d_out;

  char* p = (char*)d_ws;
  unsigned short* xb = (unsigned short*)p;    p += (size_t)NROWS * ND * 2;
  unsigned short* Wqb = (unsigned short*)p;   p += (size_t)ND * ND * 2;
  unsigned short* Wdkvb = (unsigned short*)p; p += (size_t)NDC * ND * 2;
  unsigned short* Wukb = (unsigned short*)p;  p += (size_t)ND * NDC * 2;
  unsigned short* Wuvb = (unsigned short*)p;  p += (size_t)ND * NDC * 2;
  unsigned short* Wob = (unsigned short*)p;   p += (size_t)ND * ND * 2;
  unsigned short* Qb = (unsigned short*)p;    p += (size_t)NROWS * ND * 2;
  unsigned short* ckv = (unsigned short*)p;   p += (size_t)NROWS * NDC * 2;
  unsigned short* Kbf = (unsigned short*)p;   p += (size_t)NROWS * ND * 2;
  unsigned short* Vbf = (unsigned short*)p;   p += (size_t)NROWS * ND * 2;
  unsigned short* AO = (unsigned short*)p;    p += (size_t)NROWS * ND * 2;

  // fp32 -> bf16
  {
    struct { const float* s; unsigned short* d; long n; } cv[6] = {
      {x, xb, (long)NROWS * ND},
      {W_q, Wqb, (long)ND * ND},
      {W_dkv, Wdkvb, (long)NDC * ND},
      {W_uk, Wukb, (long)ND * NDC},
      {W_uv, Wuvb, (long)ND * NDC},
      {W_o, Wob, (long)ND * ND},
    };
    for (int i = 0; i < 6; ++i) {
      int n4 = (int)(cv[i].n / 4);
      int blocks = (n4 + 255) / 256;
      if (blocks > 2048) blocks = 2048;
      cvt_kernel<<<blocks, 256, 0, stream>>>((const float4*)cv[i].s, (ushort4*)cv[i].d, n4);
    }
  }

  // projections
  gemm_nt<0><<<dim3(ND / 128, NROWS / 128), 256, 0, stream>>>(xb, Wqb, Qb, NROWS, ND, ND);
  gemm_nt<0><<<dim3(NDC / 128, NROWS / 128), 256, 0, stream>>>(xb, Wdkvb, ckv, NROWS, NDC, ND);
  gemm_nt<0><<<dim3(ND / 128, NROWS / 128), 256, 0, stream>>>(ckv, Wukb, Kbf, NROWS, ND, NDC);
  gemm_nt<0><<<dim3(ND / 128, NROWS / 128), 256, 0, stream>>>(ckv, Wuvb, Vbf, NROWS, ND, NDC);

  // RoPE (scale folded into Q)
  const float scale = 0.08838834764831845f; // 1/sqrt(128)
  rope_kernel<<<NROWS, 256, 0, stream>>>(Qb, rope_cos, rope_sin, scale);
  rope_kernel<<<NROWS, 256, 0, stream>>>(Kbf, rope_cos, rope_sin, 1.0f);

  // attention
  flash_attn<<<dim3(NL / 64, NB * NH), 256, 0, stream>>>(Qb, Kbf, Vbf, AO);

  // output projection (fp32 out)
  gemm_nt<1><<<dim3(ND / 128, NROWS / 128), 256, 0, stream>>>(AO, Wob, out, NROWS, ND, ND);
}

// Round 2
// 684.505 us; speedup vs baseline: 1.2457x; 1.2457x over previous
//
#include <hip/hip_runtime.h>
#include <math.h>

typedef __attribute__((ext_vector_type(8))) short bf16x8;
typedef __attribute__((ext_vector_type(4))) float f32x4;

#define NB 4
#define NL 2048
#define ND 2048
#define NH 16
#define NDH 128
#define NDC 512
#define NROWS (NB*NL)

__device__ __forceinline__ unsigned short f2bf(float f) {
  unsigned int u = __float_as_uint(f);
  u += 0x7fffu + ((u >> 16) & 1u);
  return (unsigned short)(u >> 16);
}
__device__ __forceinline__ float bf2f(unsigned short h) {
  return __uint_as_float(((unsigned int)h) << 16);
}

__device__ __forceinline__ void gld16(const void* g, void* l) {
  __builtin_amdgcn_global_load_lds((const __attribute__((address_space(1))) void*)g,
                                   (__attribute__((address_space(3))) void*)l, 16, 0, 0);
}

// ---------------- fp32 -> bf16 convert ----------------
__global__ void cvt_kernel(const float4* __restrict__ in, ushort4* __restrict__ out, int n4) {
  int stride = gridDim.x * blockDim.x;
  for (int i = blockIdx.x * blockDim.x + threadIdx.x; i < n4; i += stride) {
    float4 v = in[i];
    ushort4 o;
    o.x = f2bf(v.x); o.y = f2bf(v.y); o.z = f2bf(v.z); o.w = f2bf(v.w);
    out[i] = o;
  }
}

// ---------------- NT GEMM: C[M,N] = A[M,K] * B[N,K]^T (bf16 in, fp32 acc) ----------------
// 128x128 tile, BK=32, 256 threads = 4 waves in 2x2, each wave 64x64 (4x4 frags of 16x16x32)
template<int OUT_F32>
__global__ __launch_bounds__(256) void gemm_nt(const unsigned short* __restrict__ A,
                                               const unsigned short* __restrict__ Bm,
                                               void* __restrict__ Cv,
                                               int M, int N, int K) {
  __shared__ unsigned short As[128 * 32];
  __shared__ unsigned short Bs[128 * 32];
  const int tid = threadIdx.x;
  const int wid = tid >> 6;
  const int lane = tid & 63;
  const int wr = wid >> 1, wc = wid & 1;
  const long bm = blockIdx.y, bn = blockIdx.x;
  const int r15 = lane & 15;
  const int koff = (lane >> 4) * 8;
  const int srow = lane >> 2;          // 0..15 within wave's 16-row slab
  const int scol = (lane & 3) * 8;

  f32x4 acc[4][4];
#pragma unroll
  for (int m = 0; m < 4; ++m)
#pragma unroll
    for (int n = 0; n < 4; ++n) acc[m][n] = (f32x4){0.f, 0.f, 0.f, 0.f};

  const unsigned short* Ablk = A + (bm * 128 + wid * 16 + srow) * (long)K + scol;
  const unsigned short* Bblk = Bm + (bn * 128 + wid * 16 + srow) * (long)K + scol;
  unsigned short* AsW = As + wid * 16 * 32;   // wave-uniform LDS dest base
  unsigned short* BsW = Bs + wid * 16 * 32;

  for (int kk = 0; kk < K; kk += 32) {
    __syncthreads();
#pragma unroll
    for (int j = 0; j < 2; ++j) {
      gld16(Ablk + (long)j * 64 * K + kk, AsW + j * 64 * 32);
      gld16(Bblk + (long)j * 64 * K + kk, BsW + j * 64 * 32);
    }
    __syncthreads();
    bf16x8 af[4], bfr[4];
#pragma unroll
    for (int m = 0; m < 4; ++m)
      af[m] = *(const bf16x8*)(As + (wr * 64 + m * 16 + r15) * 32 + koff);
#pragma unroll
    for (int n = 0; n < 4; ++n)
      bfr[n] = *(const bf16x8*)(Bs + (wc * 64 + n * 16 + r15) * 32 + koff);
#pragma unroll
    for (int m = 0; m < 4; ++m)
#pragma unroll
      for (int n = 0; n < 4; ++n)
        acc[m][n] = __builtin_amdgcn_mfma_f32_16x16x32_bf16(af[m], bfr[n], acc[m][n], 0, 0, 0);
  }

  const int rr = (lane >> 4) * 4;
#pragma unroll
  for (int m = 0; m < 4; ++m) {
#pragma unroll
    for (int n = 0; n < 4; ++n) {
      long row0 = bm * 128 + wr * 64 + m * 16 + rr;
      long col = bn * 128 + wc * 64 + n * 16 + r15;
#pragma unroll
      for (int r = 0; r < 4; ++r) {
        float v = acc[m][n][r];
        if (OUT_F32) ((float*)Cv)[(row0 + r) * (long)N + col] = v;
        else ((unsigned short*)Cv)[(row0 + r) * (long)N + col] = f2bf(v);
      }
    }
  }
}

// ---------------- RoPE in-place on (NROWS, ND) bf16, per-head pairs (d, d+64) ----------------
__global__ void rope_kernel(unsigned short* __restrict__ Qb, const float* __restrict__ cosb,
                            const float* __restrict__ sinb, float scale) {
  const long row = blockIdx.x;
  const float* cr = cosb + row * NDH;
  const float* sr = sinb + row * NDH;
  unsigned short* q = Qb + row * (long)ND;
  for (int p = threadIdx.x; p < NH * 64; p += blockDim.x) {
    int h = p >> 6, d = p & 63;
    int i1 = h * 128 + d, i2 = i1 + 64;
    float q1 = bf2f(q[i1]), q2 = bf2f(q[i2]);
    float c1 = cr[d], c2 = cr[d + 64], s1 = sr[d], s2 = sr[d + 64];
    float o1 = (q1 * c1 - q2 * s1) * scale;
    float o2 = (q2 * c2 + q1 * s2) * scale;
    q[i1] = f2bf(o1);
    q[i2] = f2bf(o2);
  }
}

// ---------------- Flash attention v2 ----------------
// grid (NL/128, NB*NH); 512 thr = 8 waves; wave owns 16 Q rows (QBLK=128); KV tile = 64 keys
// T14 async-stage: next tile's K/V global loads issued into regs before compute,
// written to LDS after the next barrier.
__global__ __launch_bounds__(512) void flash_attn(const unsigned short* __restrict__ Qb,
                                                  const unsigned short* __restrict__ Kb,
                                                  const unsigned short* __restrict__ Vb,
                                                  unsigned short* __restrict__ Ob) {
  __shared__ unsigned short Ks[64 * 136];      // 64 keys x 128 d, pad +8
  __shared__ unsigned short Vt[128 * 72];      // transposed: d x keys, pad +8, key XOR-swizzled
  __shared__ unsigned short Ps[8][16 * 72];    // per-wave P tile, pad +8

  const int tid = threadIdx.x, wid = tid >> 6, lane = tid & 63;
  const int r15 = lane & 15, khi = lane >> 4;
  const int bh = blockIdx.y, qt = blockIdx.x;
  const int b = bh >> 4, h = bh & 15;
  const long rowbase = (long)b * NL;
  const int colbase = h * NDH;

  // Q fragments (rows qt*128 + wid*16 + r15, k chunks of 32)
  bf16x8 qf[4];
  {
    const unsigned short* qp =
        Qb + (rowbase + qt * 128 + wid * 16 + r15) * (long)ND + colbase + khi * 8;
#pragma unroll
    for (int kc = 0; kc < 4; ++kc) qf[kc] = *(const bf16x8*)(qp + kc * 32);
  }

  f32x4 oacc[8];
#pragma unroll
  for (int dt = 0; dt < 8; ++dt) oacc[dt] = (f32x4){0.f, 0.f, 0.f, 0.f};
  float mrow[4] = {-1e30f, -1e30f, -1e30f, -1e30f};
  float lrow[4] = {0.f, 0.f, 0.f, 0.f};

  // staging coords: this thread covers c = tid + 512*j, j=0..1
  const int key0 = tid >> 4;                // c>>4 for j=0  (0..31)
  const int c8 = (tid & 15) * 8;
  bf16x8 kreg[2], vreg[2];

  // prefetch tile 0
#pragma unroll
  for (int j = 0; j < 2; ++j) {
    const long grow = (rowbase + key0 + 32 * j) * (long)ND + colbase + c8;
    kreg[j] = *(const bf16x8*)(Kb + grow);
    vreg[j] = *(const bf16x8*)(Vb + grow);
  }

  for (int kt = 0; kt < NL / 64; ++kt) {
    __syncthreads();     // previous compute done reading LDS
    // write staged regs -> LDS
#pragma unroll
    for (int j = 0; j < 2; ++j) {
      int key = key0 + 32 * j;
      *(bf16x8*)(Ks + key * 136 + c8) = kreg[j];
#pragma unroll
      for (int i = 0; i < 8; ++i) {
        int d = c8 + i;
        int kcol = key ^ (((d >> 3) & 7) << 3);
        Vt[d * 72 + kcol] = (unsigned short)vreg[j][i];
      }
    }
    __syncthreads();     // LDS ready
    // prefetch next tile into regs (consumed at next iteration's write)
    if (kt + 1 < NL / 64) {
#pragma unroll
      for (int j = 0; j < 2; ++j) {
        const long grow = (rowbase + (kt + 1) * 64 + key0 + 32 * j) * (long)ND + colbase + c8;
        kreg[j] = *(const bf16x8*)(Kb + grow);
        vreg[j] = *(const bf16x8*)(Vb + grow);
      }
    }

    // S = Q K^T  (wave's 16 rows x 64 keys)
    f32x4 sacc[4];
#pragma unroll
    for (int n = 0; n < 4; ++n) {
      sacc[n] = (f32x4){0.f, 0.f, 0.f, 0.f};
#pragma unroll
      for (int kc = 0; kc < 4; ++kc) {
        bf16x8 kf = *(const bf16x8*)(Ks + (n * 16 + r15) * 136 + kc * 32 + khi * 8);
        sacc[n] = __builtin_amdgcn_mfma_f32_16x16x32_bf16(qf[kc], kf, sacc[n], 0, 0, 0);
      }
    }

    // online softmax per owned row slot r (row = khi*4 + r)
#pragma unroll
    for (int r = 0; r < 4; ++r) {
      float v = fmaxf(fmaxf(sacc[0][r], sacc[1][r]), fmaxf(sacc[2][r], sacc[3][r]));
      v = fmaxf(v, __shfl_xor(v, 1));
      v = fmaxf(v, __shfl_xor(v, 2));
      v = fmaxf(v, __shfl_xor(v, 4));
      v = fmaxf(v, __shfl_xor(v, 8));
      float mnew = fmaxf(mrow[r], v);
      float corr = __expf(mrow[r] - mnew);
      mrow[r] = mnew;
      float ps = 0.f;
#pragma unroll
      for (int n = 0; n < 4; ++n) {
        float pv = __expf(sacc[n][r] - mnew);
        sacc[n][r] = pv;
        ps += pv;
      }
      ps += __shfl_xor(ps, 1);
      ps += __shfl_xor(ps, 2);
      ps += __shfl_xor(ps, 4);
      ps += __shfl_xor(ps, 8);
      lrow[r] = lrow[r] * corr + ps;
#pragma unroll
      for (int dt = 0; dt < 8; ++dt) oacc[dt][r] *= corr;
      int prow = khi * 4 + r;
#pragma unroll
      for (int n = 0; n < 4; ++n)
        Ps[wid][prow * 72 + n * 16 + r15] = f2bf(sacc[n][r]);
    }
    asm volatile("s_waitcnt lgkmcnt(0)" ::: "memory");
    __builtin_amdgcn_sched_barrier(0);

    // PV: oacc += P(16x64) * V(64x128)
#pragma unroll
    for (int kc2 = 0; kc2 < 2; ++kc2) {
      bf16x8 pa = *(const bf16x8*)(Ps[wid] + r15 * 72 + kc2 * 32 + khi * 8);
#pragma unroll
      for (int dt = 0; dt < 8; ++dt) {
        int d = dt * 16 + r15;
        int kb = (kc2 * 32 + khi * 8) ^ (((d >> 3) & 7) << 3);
        bf16x8 vf = *(const bf16x8*)(Vt + d * 72 + kb);
        oacc[dt] = __builtin_amdgcn_mfma_f32_16x16x32_bf16(pa, vf, oacc[dt], 0, 0, 0);
      }
    }
  }

  // epilogue: O / l -> bf16
#pragma unroll
  for (int dt = 0; dt < 8; ++dt) {
#pragma unroll
    for (int r = 0; r < 4; ++r) {
      long row = rowbase + qt * 128 + wid * 16 + khi * 4 + r;
      float v = oacc[dt][r] / lrow[r];
      Ob[row * (long)ND + colbase + dt * 16 + r15] = f2bf(v);
    }
  }
}

// ---------------- launch ----------------
extern "C" void kernel_launch(void* const* d_in, const int* in_sizes, int n_in,
                              void* d_out, int out_size, void* d_ws, size_t ws_size,
                              hipStream_t stream) {
  const float* x = (const float*)d_in[0];
  const float* rope_cos = (const float*)d_in[1];
  const float* rope_sin = (const float*)d_in[2];
  const float* W_q = (const float*)d_in[3];
  const float* W_dkv = (const float*)d_in[4];
  const float* W_uk = (const float*)d_in[5];
  const float* W_uv = (const float*)d_in[6];
  const float* W_o = (const float*)d_in[7];
  float* out = (float*)d_out;

  char* p = (char*)d_ws;
  unsigned short* xb = (unsigned short*)p;    p += (size_t)NROWS * ND * 2;
  unsigned short* Wqb = (unsigned short*)p;   p += (size_t)ND * ND * 2;
  unsigned short* Wdkvb = (unsigned short*)p; p += (size_t)NDC * ND * 2;
  unsigned short* Wukb = (unsigned short*)p;  p += (size_t)ND * NDC * 2;
  unsigned short* Wuvb = (unsigned short*)p;  p += (size_t)ND * NDC * 2;
  unsigned short* Wob = (unsigned short*)p;   p += (size_t)ND * ND * 2;
  unsigned short* Qb = (unsigned short*)p;    p += (size_t)NROWS * ND * 2;
  unsigned short* ckv = (unsigned short*)p;   p += (size_t)NROWS * NDC * 2;
  unsigned short* Kbf = (unsigned short*)p;   p += (size_t)NROWS * ND * 2;
  unsigned short* Vbf = (unsigned short*)p;   p += (size_t)NROWS * ND * 2;
  unsigned short* AO = (unsigned short*)p;    p += (size_t)NROWS * ND * 2;

  // fp32 -> bf16
  {
    struct { const float* s; unsigned short* d; long n; } cv[6] = {
      {x, xb, (long)NROWS * ND},
      {W_q, Wqb, (long)ND * ND},
      {W_dkv, Wdkvb, (long)NDC * ND},
      {W_uk, Wukb, (long)ND * NDC},
      {W_uv, Wuvb, (long)ND * NDC},
      {W_o, Wob, (long)ND * ND},
    };
    for (int i = 0; i < 6; ++i) {
      int n4 = (int)(cv[i].n / 4);
      int blocks = (n4 + 255) / 256;
      if (blocks > 2048) blocks = 2048;
      cvt_kernel<<<blocks, 256, 0, stream>>>((const float4*)cv[i].s, (ushort4*)cv[i].d, n4);
    }
  }

  // projections
  gemm_nt<0><<<dim3(ND / 128, NROWS / 128), 256, 0, stream>>>(xb, Wqb, Qb, NROWS, ND, ND);
  gemm_nt<0><<<dim3(NDC / 128, NROWS / 128), 256, 0, stream>>>(xb, Wdkvb, ckv, NROWS, NDC, ND);
  gemm_nt<0><<<dim3(ND / 128, NROWS / 128), 256, 0, stream>>>(ckv, Wukb, Kbf, NROWS, ND, NDC);
  gemm_nt<0><<<dim3(ND / 128, NROWS / 128), 256, 0, stream>>>(ckv, Wuvb, Vbf, NROWS, ND, NDC);

  // RoPE (scale folded into Q)
  const float scale = 0.08838834764831845f; // 1/sqrt(128)
  rope_kernel<<<NROWS, 256, 0, stream>>>(Qb, rope_cos, rope_sin, scale);
  rope_kernel<<<NROWS, 256, 0, stream>>>(Kbf, rope_cos, rope_sin, 1.0f);

  // attention
  flash_attn<<<dim3(NL / 128, NB * NH), 512, 0, stream>>>(Qb, Kbf, Vbf, AO);

  // output projection (fp32 out)
  gemm_nt<1><<<dim3(ND / 128, NROWS / 128), 256, 0, stream>>>(AO, Wob, out, NROWS, ND, ND);
}

// Round 3
// 657.797 us; speedup vs baseline: 1.2963x; 1.0406x over previous
//
#include <hip/hip_runtime.h>
#include <math.h>

typedef __attribute__((ext_vector_type(8))) short bf16x8;
typedef __attribute__((ext_vector_type(4))) float f32x4;

#define NB 4
#define NL 2048
#define ND 2048
#define NH 16
#define NDH 128
#define NDC 512
#define NROWS (NB*NL)

__device__ __forceinline__ unsigned short f2bf(float f) {
  unsigned int u = __float_as_uint(f);
  u += 0x7fffu + ((u >> 16) & 1u);
  return (unsigned short)(u >> 16);
}
__device__ __forceinline__ float bf2f(unsigned short h) {
  return __uint_as_float(((unsigned int)h) << 16);
}

__device__ __forceinline__ void gld16(const void* g, void* l) {
  __builtin_amdgcn_global_load_lds((const __attribute__((address_space(1))) void*)g,
                                   (__attribute__((address_space(3))) void*)l, 16, 0, 0);
}

// ---------------- fp32 -> bf16 convert ----------------
__global__ void cvt_kernel(const float4* __restrict__ in, ushort4* __restrict__ out, int n4) {
  int stride = gridDim.x * blockDim.x;
  for (int i = blockIdx.x * blockDim.x + threadIdx.x; i < n4; i += stride) {
    float4 v = in[i];
    ushort4 o;
    o.x = f2bf(v.x); o.y = f2bf(v.y); o.z = f2bf(v.z); o.w = f2bf(v.w);
    out[i] = o;
  }
}

// ---------------- NT GEMM: C[M,N] = A[M,K] * B[N,K]^T (bf16 in, fp32 acc) ----------------
template<int OUT_F32>
__global__ __launch_bounds__(256) void gemm_nt(const unsigned short* __restrict__ A,
                                               const unsigned short* __restrict__ Bm,
                                               void* __restrict__ Cv,
                                               int M, int N, int K) {
  __shared__ unsigned short As[128 * 32];
  __shared__ unsigned short Bs[128 * 32];
  const int tid = threadIdx.x;
  const int wid = tid >> 6;
  const int lane = tid & 63;
  const int wr = wid >> 1, wc = wid & 1;
  const long bm = blockIdx.y, bn = blockIdx.x;
  const int r15 = lane & 15;
  const int koff = (lane >> 4) * 8;
  const int srow = lane >> 2;
  const int scol = (lane & 3) * 8;

  f32x4 acc[4][4];
#pragma unroll
  for (int m = 0; m < 4; ++m)
#pragma unroll
    for (int n = 0; n < 4; ++n) acc[m][n] = (f32x4){0.f, 0.f, 0.f, 0.f};

  const unsigned short* Ablk = A + (bm * 128 + wid * 16 + srow) * (long)K + scol;
  const unsigned short* Bblk = Bm + (bn * 128 + wid * 16 + srow) * (long)K + scol;
  unsigned short* AsW = As + wid * 16 * 32;
  unsigned short* BsW = Bs + wid * 16 * 32;

  for (int kk = 0; kk < K; kk += 32) {
    __syncthreads();
#pragma unroll
    for (int j = 0; j < 2; ++j) {
      gld16(Ablk + (long)j * 64 * K + kk, AsW + j * 64 * 32);
      gld16(Bblk + (long)j * 64 * K + kk, BsW + j * 64 * 32);
    }
    __syncthreads();
    bf16x8 af[4], bfr[4];
#pragma unroll
    for (int m = 0; m < 4; ++m)
      af[m] = *(const bf16x8*)(As + (wr * 64 + m * 16 + r15) * 32 + koff);
#pragma unroll
    for (int n = 0; n < 4; ++n)
      bfr[n] = *(const bf16x8*)(Bs + (wc * 64 + n * 16 + r15) * 32 + koff);
#pragma unroll
    for (int m = 0; m < 4; ++m)
#pragma unroll
      for (int n = 0; n < 4; ++n)
        acc[m][n] = __builtin_amdgcn_mfma_f32_16x16x32_bf16(af[m], bfr[n], acc[m][n], 0, 0, 0);
  }

  const int rr = (lane >> 4) * 4;
#pragma unroll
  for (int m = 0; m < 4; ++m) {
#pragma unroll
    for (int n = 0; n < 4; ++n) {
      long row0 = bm * 128 + wr * 64 + m * 16 + rr;
      long col = bn * 128 + wc * 64 + n * 16 + r15;
#pragma unroll
      for (int r = 0; r < 4; ++r) {
        float v = acc[m][n][r];
        if (OUT_F32) ((float*)Cv)[(row0 + r) * (long)N + col] = v;
        else ((unsigned short*)Cv)[(row0 + r) * (long)N + col] = f2bf(v);
      }
    }
  }
}

// ---------------- RoPE in-place ----------------
__global__ void rope_kernel(unsigned short* __restrict__ Qb, const float* __restrict__ cosb,
                            const float* __restrict__ sinb, float scale) {
  const long row = blockIdx.x;
  const float* cr = cosb + row * NDH;
  const float* sr = sinb + row * NDH;
  unsigned short* q = Qb + row * (long)ND;
  for (int p = threadIdx.x; p < NH * 64; p += blockDim.x) {
    int h = p >> 6, d = p & 63;
    int i1 = h * 128 + d, i2 = i1 + 64;
    float q1 = bf2f(q[i1]), q2 = bf2f(q[i2]);
    float c1 = cr[d], c2 = cr[d + 64], s1 = sr[d], s2 = sr[d + 64];
    float o1 = (q1 * c1 - q2 * s1) * scale;
    float o2 = (q2 * c2 + q1 * s2) * scale;
    q[i1] = f2bf(o1);
    q[i2] = f2bf(o2);
  }
}

// ---------------- Flash attention v3 ----------------
// grid (NL/128, NB*NH); 512 thr = 8 waves; wave owns 16 Q rows; KV tile = 64 keys.
// Swapped QK^T (S^T = mfma(K,Q)): lane holds full q-row (q=lane&15) -> in-register
// softmax + in-register P transpose via ds_bpermute. No Ps LDS, no lgkm full-stop.
__global__ __launch_bounds__(512) void flash_attn(const unsigned short* __restrict__ Qb,
                                                  const unsigned short* __restrict__ Kb,
                                                  const unsigned short* __restrict__ Vb,
                                                  unsigned short* __restrict__ Ob) {
  __shared__ unsigned short Ks[64 * 128];   // elem (key,c) at Ks[key*128 + (c ^ ((key&7)<<3))]
  __shared__ unsigned short Vt[128 * 72];   // transposed: d x keys, pad +8, key XOR-swizzled

  const int tid = threadIdx.x, wid = tid >> 6, lane = tid & 63;
  const int r15 = lane & 15, khi = lane >> 4;
  const int bh = blockIdx.y, qt = blockIdx.x;
  const int b = bh >> 4, h = bh & 15;
  const long rowbase = (long)b * NL;
  const int colbase = h * NDH;

  // Q fragments (rows qt*128 + wid*16 + r15, k chunks of 32)
  bf16x8 qf[4];
  {
    const unsigned short* qp =
        Qb + (rowbase + qt * 128 + wid * 16 + r15) * (long)ND + colbase + khi * 8;
#pragma unroll
    for (int kc = 0; kc < 4; ++kc) qf[kc] = *(const bf16x8*)(qp + kc * 32);
  }

  f32x4 oacc[8];
#pragma unroll
  for (int dt = 0; dt < 8; ++dt) oacc[dt] = (f32x4){0.f, 0.f, 0.f, 0.f};
  float mrun = -1e30f, lrun = 0.f;

  // staging coords: this thread covers keys key0, key0+32 at d-cols c8..c8+7
  const int key0 = tid >> 4;                // 0..31
  const int c8 = (tid & 15) * 8;
  const int ksw = c8 ^ ((key0 & 7) << 3);   // same for key0 and key0+32
  bf16x8 kreg[2], vreg[2];

  // prefetch tile 0
#pragma unroll
  for (int j = 0; j < 2; ++j) {
    const long grow = (rowbase + key0 + 32 * j) * (long)ND + colbase + c8;
    kreg[j] = *(const bf16x8*)(Kb + grow);
    vreg[j] = *(const bf16x8*)(Vb + grow);
  }

  for (int kt = 0; kt < NL / 64; ++kt) {
    __syncthreads();     // previous compute done reading LDS
#pragma unroll
    for (int j = 0; j < 2; ++j) {
      int key = key0 + 32 * j;
      *(bf16x8*)(Ks + key * 128 + ksw) = kreg[j];
#pragma unroll
      for (int i = 0; i < 8; ++i) {
        int d = c8 + i;
        int kcol = key ^ (((d >> 3) & 7) << 3);
        Vt[d * 72 + kcol] = (unsigned short)vreg[j][i];
      }
    }
    __syncthreads();     // LDS ready
    if (kt + 1 < NL / 64) {
#pragma unroll
      for (int j = 0; j < 2; ++j) {
        const long grow = (rowbase + (kt + 1) * 64 + key0 + 32 * j) * (long)ND + colbase + c8;
        kreg[j] = *(const bf16x8*)(Kb + grow);
        vreg[j] = *(const bf16x8*)(Vb + grow);
      }
    }

    // S^T = K Q^T : sacc[n][r] = S[q=r15][key = n*16 + khi*4 + r]
    f32x4 sacc[4];
#pragma unroll
    for (int n = 0; n < 4; ++n) {
      sacc[n] = (f32x4){0.f, 0.f, 0.f, 0.f};
#pragma unroll
      for (int kc = 0; kc < 4; ++kc) {
        int row = n * 16 + r15;
        bf16x8 kf = *(const bf16x8*)(Ks + row * 128 + ((kc * 32 + khi * 8) ^ ((row & 7) << 3)));
        sacc[n] = __builtin_amdgcn_mfma_f32_16x16x32_bf16(kf, qf[kc], sacc[n], 0, 0, 0);
      }
    }

    // in-register online softmax for row q=r15 (khi-quad shares the row)
    float mx = sacc[0][0];
#pragma unroll
    for (int n = 0; n < 4; ++n)
#pragma unroll
      for (int r = 0; r < 4; ++r) mx = fmaxf(mx, sacc[n][r]);
    mx = fmaxf(mx, __shfl_xor(mx, 16));
    mx = fmaxf(mx, __shfl_xor(mx, 32));
    if (!__all(mx - mrun <= 8.f)) {        // defer-max (T13)
      float mnew = fmaxf(mrun, mx);
      float corr = __expf(mrun - mnew);
      mrun = mnew;
      lrun *= corr;
#pragma unroll
      for (int r = 0; r < 4; ++r) {
        float c4 = __shfl(corr, khi * 20 + r);   // lane (khi, khi*4+r) holds corr for q=khi*4+r
#pragma unroll
        for (int dt = 0; dt < 8; ++dt) oacc[dt][r] *= c4;
      }
    }
    float s = 0.f;
#pragma unroll
    for (int n = 0; n < 4; ++n)
#pragma unroll
      for (int r = 0; r < 4; ++r) {
        float e = __expf(sacc[n][r] - mrun);
        sacc[n][r] = e;
        s += e;
      }
    s += __shfl_xor(s, 16);
    s += __shfl_xor(s, 32);
    lrun += s;

    // pack P to bf16 pairs: pk[n][h] = keys (n*16+khi*4+2h, +2h+1) for q=r15
    unsigned int pk[4][2];
#pragma unroll
    for (int n = 0; n < 4; ++n)
#pragma unroll
      for (int hh = 0; hh < 2; ++hh)
        pk[n][hh] = (unsigned int)f2bf(sacc[n][2 * hh]) |
                    ((unsigned int)f2bf(sacc[n][2 * hh + 1]) << 16);

    // build pa[kc2] in-register (A-frag: lane needs P[q=r15][k=kc2*32+khi*8+j]) + PV
#pragma unroll
    for (int kc2 = 0; kc2 < 2; ++kc2) {
      union { unsigned int u[4]; bf16x8 v; } pa;
#pragma unroll
      for (int w = 0; w < 4; ++w) {
        int src = ((((khi << 1) + (w >> 1)) & 3) << 4) + r15;
        unsigned int lo = (unsigned int)__shfl((int)pk[kc2 * 2][w & 1], src);
        unsigned int hi = (unsigned int)__shfl((int)pk[kc2 * 2 + 1][w & 1], src);
        pa.u[w] = (khi & 2) ? hi : lo;
      }
#pragma unroll
      for (int dt = 0; dt < 8; ++dt) {
        int d = dt * 16 + r15;
        int kb = (kc2 * 32 + khi * 8) ^ (((d >> 3) & 7) << 3);
        bf16x8 vf = *(const bf16x8*)(Vt + d * 72 + kb);
        oacc[dt] = __builtin_amdgcn_mfma_f32_16x16x32_bf16(pa.v, vf, oacc[dt], 0, 0, 0);
      }
    }
  }

  // epilogue: O / l -> bf16 (l lives at lane (*, q); pull for q = khi*4+r)
  float lr[4];
#pragma unroll
  for (int r = 0; r < 4; ++r) lr[r] = __shfl(lrun, khi * 20 + r);
#pragma unroll
  for (int dt = 0; dt < 8; ++dt) {
#pragma unroll
    for (int r = 0; r < 4; ++r) {
      long row = rowbase + qt * 128 + wid * 16 + khi * 4 + r;
      float v = oacc[dt][r] / lr[r];
      Ob[row * (long)ND + colbase + dt * 16 + r15] = f2bf(v);
    }
  }
}

// ---------------- launch ----------------
extern "C" void kernel_launch(void* const* d_in, const int* in_sizes, int n_in,
                              void* d_out, int out_size, void* d_ws, size_t ws_size,
                              hipStream_t stream) {
  const float* x = (const float*)d_in[0];
  const float* rope_cos = (const float*)d_in[1];
  const float* rope_sin = (const float*)d_in[2];
  const float* W_q = (const float*)d_in[3];
  const float* W_dkv = (const float*)d_in[4];
  const float* W_uk = (const float*)d_in[5];
  const float* W_uv = (const float*)d_in[6];
  const float* W_o = (const float*)d_in[7];
  float* out = (float*)d_out;

  char* p = (char*)d_ws;
  unsigned short* xb = (unsigned short*)p;    p += (size_t)NROWS * ND * 2;
  unsigned short* Wqb = (unsigned short*)p;   p += (size_t)ND * ND * 2;
  unsigned short* Wdkvb = (unsigned short*)p; p += (size_t)NDC * ND * 2;
  unsigned short* Wukb = (unsigned short*)p;  p += (size_t)ND * NDC * 2;
  unsigned short* Wuvb = (unsigned short*)p;  p += (size_t)ND * NDC * 2;
  unsigned short* Wob = (unsigned short*)p;   p += (size_t)ND * ND * 2;
  unsigned short* Qb = (unsigned short*)p;    p += (size_t)NROWS * ND * 2;
  unsigned short* ckv = (unsigned short*)p;   p += (size_t)NROWS * NDC * 2;
  unsigned short* Kbf = (unsigned short*)p;   p += (size_t)NROWS * ND * 2;
  unsigned short* Vbf = (unsigned short*)p;   p += (size_t)NROWS * ND * 2;
  unsigned short* AO = (unsigned short*)p;    p += (size_t)NROWS * ND * 2;

  // fp32 -> bf16
  {
    struct { const float* s; unsigned short* d; long n; } cv[6] = {
      {x, xb, (long)NROWS * ND},
      {W_q, Wqb, (long)ND * ND},
      {W_dkv, Wdkvb, (long)NDC * ND},
      {W_uk, Wukb, (long)ND * NDC},
      {W_uv, Wuvb, (long)ND * NDC},
      {W_o, Wob, (long)ND * ND},
    };
    for (int i = 0; i < 6; ++i) {
      int n4 = (int)(cv[i].n / 4);
      int blocks = (n4 + 255) / 256;
      if (blocks > 2048) blocks = 2048;
      cvt_kernel<<<blocks, 256, 0, stream>>>((const float4*)cv[i].s, (ushort4*)cv[i].d, n4);
    }
  }

  // projections
  gemm_nt<0><<<dim3(ND / 128, NROWS / 128), 256, 0, stream>>>(xb, Wqb, Qb, NROWS, ND, ND);
  gemm_nt<0><<<dim3(NDC / 128, NROWS / 128), 256, 0, stream>>>(xb, Wdkvb, ckv, NROWS, NDC, ND);
  gemm_nt<0><<<dim3(ND / 128, NROWS / 128), 256, 0, stream>>>(ckv, Wukb, Kbf, NROWS, ND, NDC);
  gemm_nt<0><<<dim3(ND / 128, NROWS / 128), 256, 0, stream>>>(ckv, Wuvb, Vbf, NROWS, ND, NDC);

  // RoPE (scale folded into Q)
  const float scale = 0.08838834764831845f; // 1/sqrt(128)
  rope_kernel<<<NROWS, 256, 0, stream>>>(Qb, rope_cos, rope_sin, scale);
  rope_kernel<<<NROWS, 256, 0, stream>>>(Kbf, rope_cos, rope_sin, 1.0f);

  // attention
  flash_attn<<<dim3(NL / 128, NB * NH), 512, 0, stream>>>(Qb, Kbf, Vbf, AO);

  // output projection (fp32 out)
  gemm_nt<1><<<dim3(ND / 128, NROWS / 128), 256, 0, stream>>>(AO, Wob, out, NROWS, ND, ND);
}

// Round 4
// 562.451 us; speedup vs baseline: 1.5160x; 1.1695x over previous
//
#include <hip/hip_runtime.h>
#include <math.h>

typedef __attribute__((ext_vector_type(8))) short bf16x8;
typedef __attribute__((ext_vector_type(4))) float f32x4;

#define NB 4
#define NL 2048
#define ND 2048
#define NH 16
#define NDH 128
#define NDC 512
#define NROWS (NB*NL)

__device__ __forceinline__ unsigned short f2bf(float f) {
  unsigned int u = __float_as_uint(f);
  u += 0x7fffu + ((u >> 16) & 1u);
  return (unsigned short)(u >> 16);
}
__device__ __forceinline__ float bf2f(unsigned short h) {
  return __uint_as_float(((unsigned int)h) << 16);
}

__device__ __forceinline__ void gld16(const void* g, void* l) {
  __builtin_amdgcn_global_load_lds((const __attribute__((address_space(1))) void*)g,
                                   (__attribute__((address_space(3))) void*)l, 16, 0, 0);
}

// ---------------- fp32 -> bf16 convert ----------------
__global__ void cvt_kernel(const float4* __restrict__ in, ushort4* __restrict__ out, int n4) {
  int stride = gridDim.x * blockDim.x;
  for (int i = blockIdx.x * blockDim.x + threadIdx.x; i < n4; i += stride) {
    float4 v = in[i];
    ushort4 o;
    o.x = f2bf(v.x); o.y = f2bf(v.y); o.z = f2bf(v.z); o.w = f2bf(v.w);
    out[i] = o;
  }
}

// ---------------- 128^2 NT GEMM (kept for N=512 shapes) ----------------
template<int OUT_F32>
__global__ __launch_bounds__(256) void gemm_nt(const unsigned short* __restrict__ A,
                                               const unsigned short* __restrict__ Bm,
                                               void* __restrict__ Cv,
                                               int M, int N, int K) {
  __shared__ unsigned short As[128 * 32];
  __shared__ unsigned short Bs[128 * 32];
  const int tid = threadIdx.x;
  const int wid = tid >> 6;
  const int lane = tid & 63;
  const int wr = wid >> 1, wc = wid & 1;
  const long bm = blockIdx.y, bn = blockIdx.x;
  const int r15 = lane & 15;
  const int koff = (lane >> 4) * 8;
  const int srow = lane >> 2;
  const int scol = (lane & 3) * 8;

  f32x4 acc[4][4];
#pragma unroll
  for (int m = 0; m < 4; ++m)
#pragma unroll
    for (int n = 0; n < 4; ++n) acc[m][n] = (f32x4){0.f, 0.f, 0.f, 0.f};

  const unsigned short* Ablk = A + (bm * 128 + wid * 16 + srow) * (long)K + scol;
  const unsigned short* Bblk = Bm + (bn * 128 + wid * 16 + srow) * (long)K + scol;
  unsigned short* AsW = As + wid * 16 * 32;
  unsigned short* BsW = Bs + wid * 16 * 32;

  for (int kk = 0; kk < K; kk += 32) {
    __syncthreads();
#pragma unroll
    for (int j = 0; j < 2; ++j) {
      gld16(Ablk + (long)j * 64 * K + kk, AsW + j * 64 * 32);
      gld16(Bblk + (long)j * 64 * K + kk, BsW + j * 64 * 32);
    }
    __syncthreads();
    bf16x8 af[4], bfr[4];
#pragma unroll
    for (int m = 0; m < 4; ++m)
      af[m] = *(const bf16x8*)(As + (wr * 64 + m * 16 + r15) * 32 + koff);
#pragma unroll
    for (int n = 0; n < 4; ++n)
      bfr[n] = *(const bf16x8*)(Bs + (wc * 64 + n * 16 + r15) * 32 + koff);
#pragma unroll
    for (int m = 0; m < 4; ++m)
#pragma unroll
      for (int n = 0; n < 4; ++n)
        acc[m][n] = __builtin_amdgcn_mfma_f32_16x16x32_bf16(af[m], bfr[n], acc[m][n], 0, 0, 0);
  }

  const int rr = (lane >> 4) * 4;
#pragma unroll
  for (int m = 0; m < 4; ++m) {
#pragma unroll
    for (int n = 0; n < 4; ++n) {
      long row0 = bm * 128 + wr * 64 + m * 16 + rr;
      long col = bn * 128 + wc * 64 + n * 16 + r15;
#pragma unroll
      for (int r = 0; r < 4; ++r) {
        float v = acc[m][n][r];
        if (OUT_F32) ((float*)Cv)[(row0 + r) * (long)N + col] = v;
        else ((unsigned short*)Cv)[(row0 + r) * (long)N + col] = f2bf(v);
      }
    }
  }
}

// ---------------- 256^2 8-phase NT GEMM (T1+T2+T3+T4+T5) ----------------
// C[M,N] = A[M,K] * B[N,K]^T. 512 thr = 8 waves (2M x 4N), BK=64, dbuf LDS 128KB.
// Per K-tile: 4 phases {stage-issue || ds_read -> barrier -> lgkm(0) -> prio1 + 16 MFMA}.
// Counted vmcnt(2) once per tile; XOR chunk swizzle (cc ^= row&7) on stage-src + read.
template<int OUT_F32>
__global__ __launch_bounds__(512) void gemm_nt256(const unsigned short* __restrict__ A,
                                                  const unsigned short* __restrict__ Bm,
                                                  void* __restrict__ Cv,
                                                  int M, int N, int K) {
  __shared__ unsigned short lds[2][2][16384];   // [buf][0=A,1=B][256 rows x 64 cols]
  const int tid = threadIdx.x;
  const int wid = tid >> 6, lane = tid & 63;
  const int wm = wid >> 2, wn = wid & 3;
  const int r15 = lane & 15, khi = lane >> 4;

  // XCD-aware bijective swizzle (nwg % 8 == 0 for all users of this kernel)
  const int gx = gridDim.x;
  int bid = blockIdx.y * gx + blockIdx.x;
  int cpx = (gx * gridDim.y) >> 3;
  int swz = (bid & 7) * cpx + (bid >> 3);
  const long bm = swz / gx, bn = swz % gx;

  // staging constants: chunk c_j = j*512 + tid; row-in-half = c>>3; chunk col = c&7
  const int c0 = tid, c1 = 512 + tid;
  const int r0 = c0 >> 3, r1 = c1 >> 3;
  const int cs0 = ((c0 & 7) ^ (r0 & 7)) * 8;    // pre-swizzled global col (elements)
  const int cs1 = ((c1 & 7) ^ (r1 & 7)) * 8;
  const unsigned short* srcA = A + (bm * 256) * (long)K;
  const unsigned short* srcB = Bm + (bn * 256) * (long)K;

#define STAGE256(mat, h, kb, bufi) do {                                              \
    const unsigned short* s_ = (mat) ? srcB : srcA;                                  \
    gld16(s_ + ((h) * 128 + r0) * (long)K + (kb) + cs0,                              \
          &lds[bufi][mat][(h) * 8192 + wid * 512]);                                  \
    gld16(s_ + ((h) * 128 + r1) * (long)K + (kb) + cs1,                              \
          &lds[bufi][mat][(h) * 8192 + 4096 + wid * 512]);                           \
  } while (0)

  f32x4 acc[8][4];
#pragma unroll
  for (int m = 0; m < 8; ++m)
#pragma unroll
    for (int n = 0; n < 4; ++n) acc[m][n] = (f32x4){0.f, 0.f, 0.f, 0.f};

  const int NT = K >> 6;
  // prologue: stage tile 0 into buf 0
  STAGE256(0, 0, 0, 0); STAGE256(0, 1, 0, 0);
  STAGE256(1, 0, 0, 0); STAGE256(1, 1, 0, 0);

  for (int t = 0; t < NT; ++t) {
    const int buf = t & 1, nbuf = buf ^ 1;
    const int kb1 = (t + 1) << 6;
    const bool pf = (t + 1 < NT);
    __builtin_amdgcn_s_barrier();                 // prev tile's reads fully drained
    if (pf) {
      STAGE256(0, 0, kb1, nbuf);
      asm volatile("s_waitcnt vmcnt(2)" ::: "memory");
    } else {
      asm volatile("s_waitcnt vmcnt(0)" ::: "memory");
    }
    __builtin_amdgcn_s_barrier();                 // tile t LDS data valid for all waves

    bf16x8 bfr[4][2];
#pragma unroll
    for (int n = 0; n < 4; ++n)
#pragma unroll
      for (int kk = 0; kk < 2; ++kk) {
        int rb = wn * 64 + n * 16 + r15;
        bfr[n][kk] = *(const bf16x8*)&lds[buf][1][rb * 64 + (((kk * 4 + khi) ^ (rb & 7)) * 8)];
      }
#pragma unroll
    for (int mb = 0; mb < 4; ++mb) {
      if (mb != 0) {
        __builtin_amdgcn_s_barrier();             // phase pacing
        if (pf) {
          if (mb == 1) STAGE256(0, 1, kb1, nbuf);
          else if (mb == 2) STAGE256(1, 0, kb1, nbuf);
          else STAGE256(1, 1, kb1, nbuf);
        }
      }
      bf16x8 af[2][2];
#pragma unroll
      for (int m2 = 0; m2 < 2; ++m2)
#pragma unroll
        for (int kk = 0; kk < 2; ++kk) {
          int ra = wm * 128 + mb * 32 + m2 * 16 + r15;
          af[m2][kk] = *(const bf16x8*)&lds[buf][0][ra * 64 + (((kk * 4 + khi) ^ (ra & 7)) * 8)];
        }
      asm volatile("s_waitcnt lgkmcnt(0)" ::: "memory");
      __builtin_amdgcn_sched_barrier(0);
      __builtin_amdgcn_s_setprio(1);
#pragma unroll
      for (int m2 = 0; m2 < 2; ++m2)
#pragma unroll
        for (int n = 0; n < 4; ++n)
#pragma unroll
          for (int kk = 0; kk < 2; ++kk)
            acc[mb * 2 + m2][n] = __builtin_amdgcn_mfma_f32_16x16x32_bf16(
                af[m2][kk], bfr[n][kk], acc[mb * 2 + m2][n], 0, 0, 0);
      __builtin_amdgcn_s_setprio(0);
    }
  }
#undef STAGE256

  // epilogue
#pragma unroll
  for (int mi = 0; mi < 8; ++mi) {
#pragma unroll
    for (int n = 0; n < 4; ++n) {
      long row0 = bm * 256 + wm * 128 + mi * 16 + khi * 4;
      long col = bn * 256 + wn * 64 + n * 16 + r15;
#pragma unroll
      for (int r = 0; r < 4; ++r) {
        float v = acc[mi][n][r];
        if (OUT_F32) ((float*)Cv)[(row0 + r) * (long)N + col] = v;
        else ((unsigned short*)Cv)[(row0 + r) * (long)N + col] = f2bf(v);
      }
    }
  }
}

// ---------------- RoPE in-place ----------------
__global__ void rope_kernel(unsigned short* __restrict__ Qb, const float* __restrict__ cosb,
                            const float* __restrict__ sinb, float scale) {
  const long row = blockIdx.x;
  const float* cr = cosb + row * NDH;
  const float* sr = sinb + row * NDH;
  unsigned short* q = Qb + row * (long)ND;
  for (int p = threadIdx.x; p < NH * 64; p += blockDim.x) {
    int h = p >> 6, d = p & 63;
    int i1 = h * 128 + d, i2 = i1 + 64;
    float q1 = bf2f(q[i1]), q2 = bf2f(q[i2]);
    float c1 = cr[d], c2 = cr[d + 64], s1 = sr[d], s2 = sr[d + 64];
    float o1 = (q1 * c1 - q2 * s1) * scale;
    float o2 = (q2 * c2 + q1 * s2) * scale;
    q[i1] = f2bf(o1);
    q[i2] = f2bf(o2);
  }
}

// ---------------- Flash attention v3 (unchanged) ----------------
__global__ __launch_bounds__(512) void flash_attn(const unsigned short* __restrict__ Qb,
                                                  const unsigned short* __restrict__ Kb,
                                                  const unsigned short* __restrict__ Vb,
                                                  unsigned short* __restrict__ Ob) {
  __shared__ unsigned short Ks[64 * 128];   // elem (key,c) at Ks[key*128 + (c ^ ((key&7)<<3))]
  __shared__ unsigned short Vt[128 * 72];   // transposed: d x keys, pad +8, key XOR-swizzled

  const int tid = threadIdx.x, wid = tid >> 6, lane = tid & 63;
  const int r15 = lane & 15, khi = lane >> 4;
  const int bh = blockIdx.y, qt = blockIdx.x;
  const int b = bh >> 4, h = bh & 15;
  const long rowbase = (long)b * NL;
  const int colbase = h * NDH;

  bf16x8 qf[4];
  {
    const unsigned short* qp =
        Qb + (rowbase + qt * 128 + wid * 16 + r15) * (long)ND + colbase + khi * 8;
#pragma unroll
    for (int kc = 0; kc < 4; ++kc) qf[kc] = *(const bf16x8*)(qp + kc * 32);
  }

  f32x4 oacc[8];
#pragma unroll
  for (int dt = 0; dt < 8; ++dt) oacc[dt] = (f32x4){0.f, 0.f, 0.f, 0.f};
  float mrun = -1e30f, lrun = 0.f;

  const int key0 = tid >> 4;
  const int c8 = (tid & 15) * 8;
  const int ksw = c8 ^ ((key0 & 7) << 3);
  bf16x8 kreg[2], vreg[2];

#pragma unroll
  for (int j = 0; j < 2; ++j) {
    const long grow = (rowbase + key0 + 32 * j) * (long)ND + colbase + c8;
    kreg[j] = *(const bf16x8*)(Kb + grow);
    vreg[j] = *(const bf16x8*)(Vb + grow);
  }

  for (int kt = 0; kt < NL / 64; ++kt) {
    __syncthreads();
#pragma unroll
    for (int j = 0; j < 2; ++j) {
      int key = key0 + 32 * j;
      *(bf16x8*)(Ks + key * 128 + ksw) = kreg[j];
#pragma unroll
      for (int i = 0; i < 8; ++i) {
        int d = c8 + i;
        int kcol = key ^ (((d >> 3) & 7) << 3);
        Vt[d * 72 + kcol] = (unsigned short)vreg[j][i];
      }
    }
    __syncthreads();
    if (kt + 1 < NL / 64) {
#pragma unroll
      for (int j = 0; j < 2; ++j) {
        const long grow = (rowbase + (kt + 1) * 64 + key0 + 32 * j) * (long)ND + colbase + c8;
        kreg[j] = *(const bf16x8*)(Kb + grow);
        vreg[j] = *(const bf16x8*)(Vb + grow);
      }
    }

    f32x4 sacc[4];
#pragma unroll
    for (int n = 0; n < 4; ++n) {
      sacc[n] = (f32x4){0.f, 0.f, 0.f, 0.f};
#pragma unroll
      for (int kc = 0; kc < 4; ++kc) {
        int row = n * 16 + r15;
        bf16x8 kf = *(const bf16x8*)(Ks + row * 128 + ((kc * 32 + khi * 8) ^ ((row & 7) << 3)));
        sacc[n] = __builtin_amdgcn_mfma_f32_16x16x32_bf16(kf, qf[kc], sacc[n], 0, 0, 0);
      }
    }

    float mx = sacc[0][0];
#pragma unroll
    for (int n = 0; n < 4; ++n)
#pragma unroll
      for (int r = 0; r < 4; ++r) mx = fmaxf(mx, sacc[n][r]);
    mx = fmaxf(mx, __shfl_xor(mx, 16));
    mx = fmaxf(mx, __shfl_xor(mx, 32));
    if (!__all(mx - mrun <= 8.f)) {
      float mnew = fmaxf(mrun, mx);
      float corr = __expf(mrun - mnew);
      mrun = mnew;
      lrun *= corr;
#pragma unroll
      for (int r = 0; r < 4; ++r) {
        float c4 = __shfl(corr, khi * 20 + r);
#pragma unroll
        for (int dt = 0; dt < 8; ++dt) oacc[dt][r] *= c4;
      }
    }
    float s = 0.f;
#pragma unroll
    for (int n = 0; n < 4; ++n)
#pragma unroll
      for (int r = 0; r < 4; ++r) {
        float e = __expf(sacc[n][r] - mrun);
        sacc[n][r] = e;
        s += e;
      }
    s += __shfl_xor(s, 16);
    s += __shfl_xor(s, 32);
    lrun += s;

    unsigned int pk[4][2];
#pragma unroll
    for (int n = 0; n < 4; ++n)
#pragma unroll
      for (int hh = 0; hh < 2; ++hh)
        pk[n][hh] = (unsigned int)f2bf(sacc[n][2 * hh]) |
                    ((unsigned int)f2bf(sacc[n][2 * hh + 1]) << 16);

#pragma unroll
    for (int kc2 = 0; kc2 < 2; ++kc2) {
      union { unsigned int u[4]; bf16x8 v; } pa;
#pragma unroll
      for (int w = 0; w < 4; ++w) {
        int src = ((((khi << 1) + (w >> 1)) & 3) << 4) + r15;
        unsigned int lo = (unsigned int)__shfl((int)pk[kc2 * 2][w & 1], src);
        unsigned int hi = (unsigned int)__shfl((int)pk[kc2 * 2 + 1][w & 1], src);
        pa.u[w] = (khi & 2) ? hi : lo;
      }
#pragma unroll
      for (int dt = 0; dt < 8; ++dt) {
        int d = dt * 16 + r15;
        int kb = (kc2 * 32 + khi * 8) ^ (((d >> 3) & 7) << 3);
        bf16x8 vf = *(const bf16x8*)(Vt + d * 72 + kb);
        oacc[dt] = __builtin_amdgcn_mfma_f32_16x16x32_bf16(pa.v, vf, oacc[dt], 0, 0, 0);
      }
    }
  }

  float lr[4];
#pragma unroll
  for (int r = 0; r < 4; ++r) lr[r] = __shfl(lrun, khi * 20 + r);
#pragma unroll
  for (int dt = 0; dt < 8; ++dt) {
#pragma unroll
    for (int r = 0; r < 4; ++r) {
      long row = rowbase + qt * 128 + wid * 16 + khi * 4 + r;
      float v = oacc[dt][r] / lr[r];
      Ob[row * (long)ND + colbase + dt * 16 + r15] = f2bf(v);
    }
  }
}

// ---------------- launch ----------------
extern "C" void kernel_launch(void* const* d_in, const int* in_sizes, int n_in,
                              void* d_out, int out_size, void* d_ws, size_t ws_size,
                              hipStream_t stream) {
  const float* x = (const float*)d_in[0];
  const float* rope_cos = (const float*)d_in[1];
  const float* rope_sin = (const float*)d_in[2];
  const float* W_q = (const float*)d_in[3];
  const float* W_dkv = (const float*)d_in[4];
  const float* W_uk = (const float*)d_in[5];
  const float* W_uv = (const float*)d_in[6];
  const float* W_o = (const float*)d_in[7];
  float* out = (float*)d_out;

  char* p = (char*)d_ws;
  unsigned short* xb = (unsigned short*)p;    p += (size_t)NROWS * ND * 2;
  unsigned short* Wqb = (unsigned short*)p;   p += (size_t)ND * ND * 2;
  unsigned short* Wdkvb = (unsigned short*)p; p += (size_t)NDC * ND * 2;
  unsigned short* Wukb = (unsigned short*)p;  p += (size_t)ND * NDC * 2;
  unsigned short* Wuvb = (unsigned short*)p;  p += (size_t)ND * NDC * 2;
  unsigned short* Wob = (unsigned short*)p;   p += (size_t)ND * ND * 2;
  unsigned short* Qb = (unsigned short*)p;    p += (size_t)NROWS * ND * 2;
  unsigned short* ckv = (unsigned short*)p;   p += (size_t)NROWS * NDC * 2;
  unsigned short* Kbf = (unsigned short*)p;   p += (size_t)NROWS * ND * 2;
  unsigned short* Vbf = (unsigned short*)p;   p += (size_t)NROWS * ND * 2;
  unsigned short* AO = (unsigned short*)p;    p += (size_t)NROWS * ND * 2;

  // fp32 -> bf16
  {
    struct { const float* s; unsigned short* d; long n; } cv[6] = {
      {x, xb, (long)NROWS * ND},
      {W_q, Wqb, (long)ND * ND},
      {W_dkv, Wdkvb, (long)NDC * ND},
      {W_uk, Wukb, (long)ND * NDC},
      {W_uv, Wuvb, (long)ND * NDC},
      {W_o, Wob, (long)ND * ND},
    };
    for (int i = 0; i < 6; ++i) {
      int n4 = (int)(cv[i].n / 4);
      int blocks = (n4 + 255) / 256;
      if (blocks > 2048) blocks = 2048;
      cvt_kernel<<<blocks, 256, 0, stream>>>((const float4*)cv[i].s, (ushort4*)cv[i].d, n4);
    }
  }

  // projections: 256^2 8-phase for nwg=256 shapes; 128^2 for dkv (N=512)
  gemm_nt256<0><<<dim3(ND / 256, NROWS / 256), 512, 0, stream>>>(xb, Wqb, Qb, NROWS, ND, ND);
  gemm_nt<0><<<dim3(NDC / 128, NROWS / 128), 256, 0, stream>>>(xb, Wdkvb, ckv, NROWS, NDC, ND);
  gemm_nt256<0><<<dim3(ND / 256, NROWS / 256), 512, 0, stream>>>(ckv, Wukb, Kbf, NROWS, ND, NDC);
  gemm_nt256<0><<<dim3(ND / 256, NROWS / 256), 512, 0, stream>>>(ckv, Wuvb, Vbf, NROWS, ND, NDC);

  // RoPE (scale folded into Q)
  const float scale = 0.08838834764831845f; // 1/sqrt(128)
  rope_kernel<<<NROWS, 256, 0, stream>>>(Qb, rope_cos, rope_sin, scale);
  rope_kernel<<<NROWS, 256, 0, stream>>>(Kbf, rope_cos, rope_sin, 1.0f);

  // attention
  flash_attn<<<dim3(NL / 128, NB * NH), 512, 0, stream>>>(Qb, Kbf, Vbf, AO);

  // output projection (fp32 out)
  gemm_nt256<1><<<dim3(ND / 256, NROWS / 256), 512, 0, stream>>>(AO, Wob, out, NROWS, ND, ND);
}

// Round 5
// 484.962 us; speedup vs baseline: 1.7583x; 1.1598x over previous
//
#include <hip/hip_runtime.h>
#include <math.h>

typedef __attribute__((ext_vector_type(8))) short bf16x8;
typedef __attribute__((ext_vector_type(4))) float f32x4;
typedef __attribute__((ext_vector_type(16))) float f32x16;

#define NB 4
#define NL 2048
#define ND 2048
#define NH 16
#define NDH 128
#define NDC 512
#define NROWS (NB*NL)

__device__ __forceinline__ unsigned short f2bf(float f) {
  unsigned int u = __float_as_uint(f);
  u += 0x7fffu + ((u >> 16) & 1u);
  return (unsigned short)(u >> 16);
}
__device__ __forceinline__ float bf2f(unsigned short h) {
  return __uint_as_float(((unsigned int)h) << 16);
}
__device__ __forceinline__ unsigned int pack2bf(float a, float b) {
  return (unsigned int)f2bf(a) | ((unsigned int)f2bf(b) << 16);
}

__device__ __forceinline__ void gld16(const void* g, void* l) {
  __builtin_amdgcn_global_load_lds((const __attribute__((address_space(1))) void*)g,
                                   (__attribute__((address_space(3))) void*)l, 16, 0, 0);
}

// ---------------- fp32 -> bf16 convert ----------------
__global__ void cvt_kernel(const float4* __restrict__ in, ushort4* __restrict__ out, int n4) {
  int stride = gridDim.x * blockDim.x;
  for (int i = blockIdx.x * blockDim.x + threadIdx.x; i < n4; i += stride) {
    float4 v = in[i];
    ushort4 o;
    o.x = f2bf(v.x); o.y = f2bf(v.y); o.z = f2bf(v.z); o.w = f2bf(v.w);
    out[i] = o;
  }
}

// ---------------- 128^2 NT GEMM (kept for N=512 shapes) ----------------
template<int OUT_F32>
__global__ __launch_bounds__(256) void gemm_nt(const unsigned short* __restrict__ A,
                                               const unsigned short* __restrict__ Bm,
                                               void* __restrict__ Cv,
                                               int M, int N, int K) {
  __shared__ unsigned short As[128 * 32];
  __shared__ unsigned short Bs[128 * 32];
  const int tid = threadIdx.x;
  const int wid = tid >> 6;
  const int lane = tid & 63;
  const int wr = wid >> 1, wc = wid & 1;
  const long bm = blockIdx.y, bn = blockIdx.x;
  const int r15 = lane & 15;
  const int koff = (lane >> 4) * 8;
  const int srow = lane >> 2;
  const int scol = (lane & 3) * 8;

  f32x4 acc[4][4];
#pragma unroll
  for (int m = 0; m < 4; ++m)
#pragma unroll
    for (int n = 0; n < 4; ++n) acc[m][n] = (f32x4){0.f, 0.f, 0.f, 0.f};

  const unsigned short* Ablk = A + (bm * 128 + wid * 16 + srow) * (long)K + scol;
  const unsigned short* Bblk = Bm + (bn * 128 + wid * 16 + srow) * (long)K + scol;
  unsigned short* AsW = As + wid * 16 * 32;
  unsigned short* BsW = Bs + wid * 16 * 32;

  for (int kk = 0; kk < K; kk += 32) {
    __syncthreads();
#pragma unroll
    for (int j = 0; j < 2; ++j) {
      gld16(Ablk + (long)j * 64 * K + kk, AsW + j * 64 * 32);
      gld16(Bblk + (long)j * 64 * K + kk, BsW + j * 64 * 32);
    }
    __syncthreads();
    bf16x8 af[4], bfr[4];
#pragma unroll
    for (int m = 0; m < 4; ++m)
      af[m] = *(const bf16x8*)(As + (wr * 64 + m * 16 + r15) * 32 + koff);
#pragma unroll
    for (int n = 0; n < 4; ++n)
      bfr[n] = *(const bf16x8*)(Bs + (wc * 64 + n * 16 + r15) * 32 + koff);
#pragma unroll
    for (int m = 0; m < 4; ++m)
#pragma unroll
      for (int n = 0; n < 4; ++n)
        acc[m][n] = __builtin_amdgcn_mfma_f32_16x16x32_bf16(af[m], bfr[n], acc[m][n], 0, 0, 0);
  }

  const int rr = (lane >> 4) * 4;
#pragma unroll
  for (int m = 0; m < 4; ++m) {
#pragma unroll
    for (int n = 0; n < 4; ++n) {
      long row0 = bm * 128 + wr * 64 + m * 16 + rr;
      long col = bn * 128 + wc * 64 + n * 16 + r15;
#pragma unroll
      for (int r = 0; r < 4; ++r) {
        float v = acc[m][n][r];
        if (OUT_F32) ((float*)Cv)[(row0 + r) * (long)N + col] = v;
        else ((unsigned short*)Cv)[(row0 + r) * (long)N + col] = f2bf(v);
      }
    }
  }
}

// ---------------- 256^2 8-phase NT GEMM (T1+T2+T3+T4+T5) ----------------
template<int OUT_F32>
__global__ __launch_bounds__(512) void gemm_nt256(const unsigned short* __restrict__ A,
                                                  const unsigned short* __restrict__ Bm,
                                                  void* __restrict__ Cv,
                                                  int M, int N, int K) {
  __shared__ unsigned short lds[2][2][16384];   // [buf][0=A,1=B][256 rows x 64 cols]
  const int tid = threadIdx.x;
  const int wid = tid >> 6, lane = tid & 63;
  const int wm = wid >> 2, wn = wid & 3;
  const int r15 = lane & 15, khi = lane >> 4;

  const int gx = gridDim.x;
  int bid = blockIdx.y * gx + blockIdx.x;
  int cpx = (gx * gridDim.y) >> 3;
  int swz = (bid & 7) * cpx + (bid >> 3);
  const long bm = swz / gx, bn = swz % gx;

  const int c0 = tid, c1 = 512 + tid;
  const int r0 = c0 >> 3, r1 = c1 >> 3;
  const int cs0 = ((c0 & 7) ^ (r0 & 7)) * 8;
  const int cs1 = ((c1 & 7) ^ (r1 & 7)) * 8;
  const unsigned short* srcA = A + (bm * 256) * (long)K;
  const unsigned short* srcB = Bm + (bn * 256) * (long)K;

#define STAGE256(mat, h, kb, bufi) do {                                              \
    const unsigned short* s_ = (mat) ? srcB : srcA;                                  \
    gld16(s_ + ((h) * 128 + r0) * (long)K + (kb) + cs0,                              \
          &lds[bufi][mat][(h) * 8192 + wid * 512]);                                  \
    gld16(s_ + ((h) * 128 + r1) * (long)K + (kb) + cs1,                              \
          &lds[bufi][mat][(h) * 8192 + 4096 + wid * 512]);                           \
  } while (0)

  f32x4 acc[8][4];
#pragma unroll
  for (int m = 0; m < 8; ++m)
#pragma unroll
    for (int n = 0; n < 4; ++n) acc[m][n] = (f32x4){0.f, 0.f, 0.f, 0.f};

  const int NT = K >> 6;
  STAGE256(0, 0, 0, 0); STAGE256(0, 1, 0, 0);
  STAGE256(1, 0, 0, 0); STAGE256(1, 1, 0, 0);

  for (int t = 0; t < NT; ++t) {
    const int buf = t & 1, nbuf = buf ^ 1;
    const int kb1 = (t + 1) << 6;
    const bool pf = (t + 1 < NT);
    __builtin_amdgcn_s_barrier();
    if (pf) {
      STAGE256(0, 0, kb1, nbuf);
      asm volatile("s_waitcnt vmcnt(2)" ::: "memory");
    } else {
      asm volatile("s_waitcnt vmcnt(0)" ::: "memory");
    }
    __builtin_amdgcn_s_barrier();

    bf16x8 bfr[4][2];
#pragma unroll
    for (int n = 0; n < 4; ++n)
#pragma unroll
      for (int kk = 0; kk < 2; ++kk) {
        int rb = wn * 64 + n * 16 + r15;
        bfr[n][kk] = *(const bf16x8*)&lds[buf][1][rb * 64 + (((kk * 4 + khi) ^ (rb & 7)) * 8)];
      }
#pragma unroll
    for (int mb = 0; mb < 4; ++mb) {
      if (mb != 0) {
        __builtin_amdgcn_s_barrier();
        if (pf) {
          if (mb == 1) STAGE256(0, 1, kb1, nbuf);
          else if (mb == 2) STAGE256(1, 0, kb1, nbuf);
          else STAGE256(1, 1, kb1, nbuf);
        }
      }
      bf16x8 af[2][2];
#pragma unroll
      for (int m2 = 0; m2 < 2; ++m2)
#pragma unroll
        for (int kk = 0; kk < 2; ++kk) {
          int ra = wm * 128 + mb * 32 + m2 * 16 + r15;
          af[m2][kk] = *(const bf16x8*)&lds[buf][0][ra * 64 + (((kk * 4 + khi) ^ (ra & 7)) * 8)];
        }
      asm volatile("s_waitcnt lgkmcnt(0)" ::: "memory");
      __builtin_amdgcn_sched_barrier(0);
      __builtin_amdgcn_s_setprio(1);
#pragma unroll
      for (int m2 = 0; m2 < 2; ++m2)
#pragma unroll
        for (int n = 0; n < 4; ++n)
#pragma unroll
          for (int kk = 0; kk < 2; ++kk)
            acc[mb * 2 + m2][n] = __builtin_amdgcn_mfma_f32_16x16x32_bf16(
                af[m2][kk], bfr[n][kk], acc[mb * 2 + m2][n], 0, 0, 0);
      __builtin_amdgcn_s_setprio(0);
    }
  }
#undef STAGE256

#pragma unroll
  for (int mi = 0; mi < 8; ++mi) {
#pragma unroll
    for (int n = 0; n < 4; ++n) {
      long row0 = bm * 256 + wm * 128 + mi * 16 + khi * 4;
      long col = bn * 256 + wn * 64 + n * 16 + r15;
#pragma unroll
      for (int r = 0; r < 4; ++r) {
        float v = acc[mi][n][r];
        if (OUT_F32) ((float*)Cv)[(row0 + r) * (long)N + col] = v;
        else ((unsigned short*)Cv)[(row0 + r) * (long)N + col] = f2bf(v);
      }
    }
  }
}

// ---------------- RoPE in-place ----------------
__global__ void rope_kernel(unsigned short* __restrict__ Qb, const float* __restrict__ cosb,
                            const float* __restrict__ sinb, float scale) {
  const long row = blockIdx.x;
  const float* cr = cosb + row * NDH;
  const float* sr = sinb + row * NDH;
  unsigned short* q = Qb + row * (long)ND;
  for (int p = threadIdx.x; p < NH * 64; p += blockDim.x) {
    int h = p >> 6, d = p & 63;
    int i1 = h * 128 + d, i2 = i1 + 64;
    float q1 = bf2f(q[i1]), q2 = bf2f(q[i2]);
    float c1 = cr[d], c2 = cr[d + 64], s1 = sr[d], s2 = sr[d + 64];
    float o1 = (q1 * c1 - q2 * s1) * scale;
    float o2 = (q2 * c2 + q1 * s2) * scale;
    q[i1] = f2bf(o1);
    q[i2] = f2bf(o2);
  }
}

// ---------------- Flash attention v4: 32x32 MFMA, 32 q/wave, QBLK=256 ----------------
// grid (NL/256, NB*NH); 512 thr = 8 waves. Swapped QK^T: mfma32(K,Q) -> S^T with
// col = q = lane&31, row = key_rel = (reg&3)+8*(reg>>2)+4*(lane>>5). Softmax fully
// lane-local (+1 xor-32 hop). P -> PV B-operand via 8 packs + 8 shfl_xor(32) per nb.
// PV: mfma32(V^T from Vt, P) -> O^T. Epilogue transposes via per-wave LDS scratch.
__global__ __launch_bounds__(512) void flash_attn(const unsigned short* __restrict__ Qb,
                                                  const unsigned short* __restrict__ Kb,
                                                  const unsigned short* __restrict__ Vb,
                                                  unsigned short* __restrict__ Ob) {
  __shared__ unsigned short ldsbuf[18432];   // Ks[64*128] | Vt[128*72]; reused as scratch[8][32*72]
  unsigned short* Ks = ldsbuf;               // elem (key,c) at Ks[key*128 + (c ^ ((key&7)<<3))]
  unsigned short* Vt = ldsbuf + 8192;        // transposed: d x keys, pad +8, key XOR-swizzled by d

  const int tid = threadIdx.x, wid = tid >> 6, lane = tid & 63;
  const int l31 = lane & 31, hi5 = lane >> 5;
  const int bh = blockIdx.y, qt = blockIdx.x;
  const int b = bh >> 4, h = bh & 15;
  const long rowbase = (long)b * NL;
  const int colbase = h * NDH;
  const long q0 = (long)qt * 256 + wid * 32;

  // Q fragments: B-operand, col = q = l31, k = kc*16 + hi5*8 + j
  bf16x8 qf[8];
  {
    const unsigned short* qp = Qb + (rowbase + q0 + l31) * (long)ND + colbase + hi5 * 8;
#pragma unroll
    for (int kc = 0; kc < 8; ++kc) qf[kc] = *(const bf16x8*)(qp + kc * 16);
  }

  f32x16 oacc[4];
#pragma unroll
  for (int db = 0; db < 4; ++db)
#pragma unroll
    for (int i = 0; i < 16; ++i) oacc[db][i] = 0.f;
  float mrun = -1e30f, lrun = 0.f;

  // staging (unchanged from v3): thread covers keys key0, key0+32 at d-cols c8..c8+7
  const int key0 = tid >> 4;
  const int c8 = (tid & 15) * 8;
  const int ksw = c8 ^ ((key0 & 7) << 3);
  bf16x8 kreg[2], vreg[2];

#pragma unroll
  for (int j = 0; j < 2; ++j) {
    const long grow = (rowbase + key0 + 32 * j) * (long)ND + colbase + c8;
    kreg[j] = *(const bf16x8*)(Kb + grow);
    vreg[j] = *(const bf16x8*)(Vb + grow);
  }

  for (int kt = 0; kt < NL / 64; ++kt) {
    __syncthreads();
#pragma unroll
    for (int j = 0; j < 2; ++j) {
      int key = key0 + 32 * j;
      *(bf16x8*)(Ks + key * 128 + ksw) = kreg[j];
#pragma unroll
      for (int i = 0; i < 8; ++i) {
        int d = c8 + i;
        int kcol = key ^ (((d >> 3) & 7) << 3);
        Vt[d * 72 + kcol] = (unsigned short)vreg[j][i];
      }
    }
    __syncthreads();
    if (kt + 1 < NL / 64) {
#pragma unroll
      for (int j = 0; j < 2; ++j) {
        const long grow = (rowbase + (kt + 1) * 64 + key0 + 32 * j) * (long)ND + colbase + c8;
        kreg[j] = *(const bf16x8*)(Kb + grow);
        vreg[j] = *(const bf16x8*)(Vb + grow);
      }
    }

    // S^T = mfma32(K, Q): sacc[nb] covers keys nb*32..+31 (rows) x 32 q (cols)
    f32x16 sacc[2];
#pragma unroll
    for (int nb = 0; nb < 2; ++nb) {
#pragma unroll
      for (int i = 0; i < 16; ++i) sacc[nb][i] = 0.f;
#pragma unroll
      for (int kc = 0; kc < 8; ++kc) {
        int row = nb * 32 + l31;
        bf16x8 kf = *(const bf16x8*)(Ks + row * 128 + ((kc * 16 + hi5 * 8) ^ ((row & 7) << 3)));
        sacc[nb] = __builtin_amdgcn_mfma_f32_32x32x16_bf16(kf, qf[kc], sacc[nb], 0, 0, 0);
      }
    }

    // lane-local online softmax for q = l31 (partner lane l^32 holds other 32 keys)
    float mx = sacc[0][0];
#pragma unroll
    for (int nb = 0; nb < 2; ++nb)
#pragma unroll
      for (int r = 0; r < 16; ++r) mx = fmaxf(mx, sacc[nb][r]);
    mx = fmaxf(mx, __shfl_xor(mx, 32));
    if (!__all(mx - mrun <= 8.f)) {            // defer-max (T13)
      float mnew = fmaxf(mrun, mx);
      float corr = __expf(mrun - mnew);
      mrun = mnew;
      lrun *= corr;
#pragma unroll
      for (int db = 0; db < 4; ++db)
#pragma unroll
        for (int i = 0; i < 16; ++i) oacc[db][i] *= corr;
    }
    float s = 0.f;
#pragma unroll
    for (int nb = 0; nb < 2; ++nb)
#pragma unroll
      for (int r = 0; r < 16; ++r) {
        float e = __expf(sacc[nb][r] - mrun);
        sacc[nb][r] = e;
        s += e;
      }
    s += __shfl_xor(s, 32);
    lrun += s;

    // P -> B-operand frags. Per nb: packs (rows by C-layout: reg r -> (r&3)+8*(r>>2)+4*hi5)
    union { unsigned int u[4]; bf16x8 v; } pa[2][2];
#pragma unroll
    for (int nb = 0; nb < 2; ++nb) {
      unsigned int x1 = pack2bf(sacc[nb][0], sacc[nb][1]);
      unsigned int x2 = pack2bf(sacc[nb][2], sacc[nb][3]);
      unsigned int y1 = pack2bf(sacc[nb][4], sacc[nb][5]);
      unsigned int y2 = pack2bf(sacc[nb][6], sacc[nb][7]);
      unsigned int z1 = pack2bf(sacc[nb][8], sacc[nb][9]);
      unsigned int z2 = pack2bf(sacc[nb][10], sacc[nb][11]);
      unsigned int w1 = pack2bf(sacc[nb][12], sacc[nb][13]);
      unsigned int w2 = pack2bf(sacc[nb][14], sacc[nb][15]);
      unsigned int sx1 = __shfl_xor((int)x1, 32), sx2 = __shfl_xor((int)x2, 32);
      unsigned int sy1 = __shfl_xor((int)y1, 32), sy2 = __shfl_xor((int)y2, 32);
      unsigned int sz1 = __shfl_xor((int)z1, 32), sz2 = __shfl_xor((int)z2, 32);
      unsigned int sw1 = __shfl_xor((int)w1, 32), sw2 = __shfl_xor((int)w2, 32);
      // ks=0: rows 0..15; hi5=0 lane needs k=0..7 (rows 0..7), hi5=1 k=8..15 (rows 8..15)
      pa[nb][0].u[0] = hi5 ? sy1 : x1;
      pa[nb][0].u[1] = hi5 ? sy2 : x2;
      pa[nb][0].u[2] = hi5 ? y1 : sx1;
      pa[nb][0].u[3] = hi5 ? y2 : sx2;
      // ks=1: rows 16..31
      pa[nb][1].u[0] = hi5 ? sw1 : z1;
      pa[nb][1].u[1] = hi5 ? sw2 : z2;
      pa[nb][1].u[2] = hi5 ? w1 : sz1;
      pa[nb][1].u[3] = hi5 ? w2 : sz2;
    }

    // PV: O^T[d][q] += V^T-frag x P-frag. A: lane holds V[key=base+hi5*8+j][d=db*32+l31]
#pragma unroll
    for (int db = 0; db < 4; ++db) {
      int d = db * 32 + l31;
      int dsw = ((d >> 3) & 7) << 3;
#pragma unroll
      for (int nb = 0; nb < 2; ++nb)
#pragma unroll
        for (int ks = 0; ks < 2; ++ks) {
          int keybase8 = nb * 32 + ks * 16 + hi5 * 8;
          bf16x8 vf = *(const bf16x8*)(Vt + d * 72 + (keybase8 ^ dsw));
          oacc[db] = __builtin_amdgcn_mfma_f32_32x32x16_bf16(vf, pa[nb][ks].v, oacc[db], 0, 0, 0);
        }
    }
  }

  // ---------- epilogue: O^T -> O via per-wave LDS scratch, coalesced stores ----------
  __syncthreads();                       // all waves done with Ks/Vt
  float rinv = 1.0f / lrun;
  unsigned short* scr = ldsbuf + wid * 2304;   // 32 rows x 72 (d-chunk of 64 + pad)
#pragma unroll
  for (int c = 0; c < 2; ++c) {          // d-chunks [0,64) and [64,128)
    asm volatile("s_waitcnt lgkmcnt(0)" ::: "memory");
    __builtin_amdgcn_sched_barrier(0);
#pragma unroll
    for (int dbh = 0; dbh < 2; ++dbh) {  // db = 2c + dbh
      int db = 2 * c + dbh;
#pragma unroll
      for (int t = 0; t < 8; ++t) {
        int d_lo = dbh * 32 + ((2 * t) & 3) + 8 * (t >> 1) + 4 * hi5;  // within chunk
        unsigned int pv = pack2bf(oacc[db][2 * t] * rinv, oacc[db][2 * t + 1] * rinv);
        *(unsigned int*)(scr + l31 * 72 + d_lo) = pv;
      }
    }
    asm volatile("s_waitcnt lgkmcnt(0)" ::: "memory");
    __builtin_amdgcn_sched_barrier(0);
    // read back rows, store coalesced: 4 insts x (8 rows x 128B)
#pragma unroll
    for (int j = 0; j < 4; ++j) {
      int row = j * 8 + (lane >> 3);
      bf16x8 ov = *(const bf16x8*)(scr + row * 72 + (lane & 7) * 8);
      *(bf16x8*)(Ob + (rowbase + q0 + row) * (long)ND + colbase + c * 64 + (lane & 7) * 8) = ov;
    }
  }
}

// ---------------- launch ----------------
extern "C" void kernel_launch(void* const* d_in, const int* in_sizes, int n_in,
                              void* d_out, int out_size, void* d_ws, size_t ws_size,
                              hipStream_t stream) {
  const float* x = (const float*)d_in[0];
  const float* rope_cos = (const float*)d_in[1];
  const float* rope_sin = (const float*)d_in[2];
  const float* W_q = (const float*)d_in[3];
  const float* W_dkv = (const float*)d_in[4];
  const float* W_uk = (const float*)d_in[5];
  const float* W_uv = (const float*)d_in[6];
  const float* W_o = (const float*)d_in[7];
  float* out = (float*)d_out;

  char* p = (char*)d_ws;
  unsigned short* xb = (unsigned short*)p;    p += (size_t)NROWS * ND * 2;
  unsigned short* Wqb = (unsigned short*)p;   p += (size_t)ND * ND * 2;
  unsigned short* Wdkvb = (unsigned short*)p; p += (size_t)NDC * ND * 2;
  unsigned short* Wukb = (unsigned short*)p;  p += (size_t)ND * NDC * 2;
  unsigned short* Wuvb = (unsigned short*)p;  p += (size_t)ND * NDC * 2;
  unsigned short* Wob = (unsigned short*)p;   p += (size_t)ND * ND * 2;
  unsigned short* Qb = (unsigned short*)p;    p += (size_t)NROWS * ND * 2;
  unsigned short* ckv = (unsigned short*)p;   p += (size_t)NROWS * NDC * 2;
  unsigned short* Kbf = (unsigned short*)p;   p += (size_t)NROWS * ND * 2;
  unsigned short* Vbf = (unsigned short*)p;   p += (size_t)NROWS * ND * 2;
  unsigned short* AO = (unsigned short*)p;    p += (size_t)NROWS * ND * 2;

  // fp32 -> bf16
  {
    struct { const float* s; unsigned short* d; long n; } cv[6] = {
      {x, xb, (long)NROWS * ND},
      {W_q, Wqb, (long)ND * ND},
      {W_dkv, Wdkvb, (long)NDC * ND},
      {W_uk, Wukb, (long)ND * NDC},
      {W_uv, Wuvb, (long)ND * NDC},
      {W_o, Wob, (long)ND * ND},
    };
    for (int i = 0; i < 6; ++i) {
      int n4 = (int)(cv[i].n / 4);
      int blocks = (n4 + 255) / 256;
      if (blocks > 2048) blocks = 2048;
      cvt_kernel<<<blocks, 256, 0, stream>>>((const float4*)cv[i].s, (ushort4*)cv[i].d, n4);
    }
  }

  // projections: 256^2 8-phase for nwg=256 shapes; 128^2 for dkv (N=512)
  gemm_nt256<0><<<dim3(ND / 256, NROWS / 256), 512, 0, stream>>>(xb, Wqb, Qb, NROWS, ND, ND);
  gemm_nt<0><<<dim3(NDC / 128, NROWS / 128), 256, 0, stream>>>(xb, Wdkvb, ckv, NROWS, NDC, ND);
  gemm_nt256<0><<<dim3(ND / 256, NROWS / 256), 512, 0, stream>>>(ckv, Wukb, Kbf, NROWS, ND, NDC);
  gemm_nt256<0><<<dim3(ND / 256, NROWS / 256), 512, 0, stream>>>(ckv, Wuvb, Vbf, NROWS, ND, NDC);

  // RoPE (scale folded into Q)
  const float scale = 0.08838834764831845f; // 1/sqrt(128)
  rope_kernel<<<NROWS, 256, 0, stream>>>(Qb, rope_cos, rope_sin, scale);
  rope_kernel<<<NROWS, 256, 0, stream>>>(Kbf, rope_cos, rope_sin, 1.0f);

  // attention
  flash_attn<<<dim3(NL / 256, NB * NH), 512, 0, stream>>>(Qb, Kbf, Vbf, AO);

  // output projection (fp32 out)
  gemm_nt256<1><<<dim3(ND / 256, NROWS / 256), 512, 0, stream>>>(AO, Wob, out, NROWS, ND, ND);
}